// Round 17
// baseline (35.718 us; speedup 1.0000x reference)
//
#include <hip/hip_runtime.h>

// VectorQuantizer on MI355X (gfx950) — v17 = v14 minus the sched_barrier pin.
// out[0 .. 8388607] = codebook[argmin_k ||z - E_k||^2]   (f32)
// out[8388608]      = 1.25 * mean((z_q - z)^2)           (f32)
//
// Score: maximize  s = fp8(z).fp8(1024 E_k) via mfma_f32_16x16x32_fp8_fp8 with
// C = 128 (positivity bias); the ||E||^2/2 metric term (span ±0.006 « fp8
// noise 0.2) is dropped from scoring and restored exactly in the loss via
// eps2[bi] (v13-proven neutral).  Key = (bits(s+128) & 0xFFFFFC00) |
// (1023-col); u32 max = argmax + earliest-col tie-break (np.argmin).
// Loss: ||q-z||^2 = ||z||^2 + (128 - v* + eps2[bi])/512, per-block partial ->
// ONE plain device-scope float atomicAdd into out[8388608] (v16-proven
// neutral; prep zero-inits).  2-kernel chain.
//
// v17 isolation: v14 = {2-chunk streaming (+0.8 in v11), fused atomic
// (neutral, v16), sched_barrier(0) pin (UNTESTED)} regressed to 35.6.
// Deleting ONLY the pin tests whether the pin was the toxin and whether
// unpinned 2-chunk streaming (chunk-1 z-loads under sweep-0, chunk-0 writes
// drain under sweep-1) beats the 30.8/31.1 plateau.

typedef __attribute__((ext_vector_type(4))) float f32x4;
typedef __attribute__((ext_vector_type(2))) long long llx2;

#define N_TOKENS 131072
#define DIM 64
#define DYN_LDS 65536   // 64 KB fp8 codebook (permuted)

// ---------------- kernel 1: codebook prep (fp8 permuted + eps2) ---------------
// Permuted row layout, byte b (0..63): c=b>>4 (16B chunk), kk=(b>>3)&1, j=b&7
// holds fp8(E'[kk*32 + c*8 + j]).
__global__ __launch_bounds__(256) void vq_prep8(
    const float* __restrict__ cb, unsigned* __restrict__ ch8,
    float* __restrict__ eps2, float* __restrict__ out_loss) {
  const int t = threadIdx.x;
  const int code = blockIdx.x * 16 + (t >> 4);   // 64 blocks * 16 codes
  const int l = t & 15;                          // dword slot within 64B row
  const int k0 = ((l >> 1) & 1) * 32 + (l >> 2) * 8 + (l & 1) * 4;
  const f32x4 v = *(const f32x4*)(cb + code * DIM + k0);
  const float e0 = v[0] * 1024.0f, e1 = v[1] * 1024.0f;
  const float e2 = v[2] * 1024.0f, e3 = v[3] * 1024.0f;
  unsigned p = __builtin_amdgcn_cvt_pk_fp8_f32(e0, e1, 0, false);
  p = __builtin_amdgcn_cvt_pk_fp8_f32(e2, e3, p, true);
  ch8[code * 16 + l] = p;
  float sq = e0 * e0 + e1 * e1 + e2 * e2 + e3 * e3;
  #pragma unroll
  for (int w = 1; w < 16; w <<= 1) sq += __shfl_xor(sq, w, 64);
  if (l == 0) eps2[code] = sq * (1.0f / 2048.0f);
  if (blockIdx.x == 0 && t == 0) out_loss[0] = 0.0f;   // loss accumulator init
}

// ---------------- kernel 2: argmin + gather + loss (2-chunk streaming) --------
__global__ __attribute__((amdgpu_flat_work_group_size(256, 256),
                          amdgpu_waves_per_eu(2, 2)))
void vq_argmin(
    const float* __restrict__ z, const unsigned* __restrict__ ch8,
    const float* __restrict__ eps2, const float* __restrict__ cb,
    float* __restrict__ out) {
  extern __shared__ char lds[];
  unsigned* B8 = (unsigned*)lds;                 // 64 KB: [1024 codes][16 dwords]
  __shared__ float sml[4];

  const int tid = threadIdx.x, lane = tid & 63, wv = tid >> 6;
  const int g = lane >> 4, c15 = lane & 15;
  const size_t wrow = (size_t)blockIdx.x * 256 + (size_t)wv * 64;  // 64 rows/wave
  const unsigned kmask = 0xFFFFFC00u;

  // ---- DMA-stage fp8 codebook; source XOR-swizzled 16B chunks, dest linear
  #pragma unroll
  for (int q = 0; q < 16; ++q) {
    const int chunk = q * 256 + tid;             // 16B chunk id, 0..4095
    const int code = chunk >> 2, c2 = chunk & 3;
    __builtin_amdgcn_global_load_lds(
        (const __attribute__((address_space(1))) unsigned int*)
            (ch8 + code * 16 + ((c2 ^ (code & 3)) << 2)),
        (__attribute__((address_space(3))) unsigned int*)(B8 + chunk * 4),
        16, 0, 0);
  }

  // ---- chunk-0 A loads (rows 0..31), in flight across the barrier
  f32x4 a0[2][2][2];
  const float* zb = z + wrow * DIM;
  #pragma unroll
  for (int m = 0; m < 2; ++m)
    #pragma unroll
    for (int kk = 0; kk < 2; ++kk) {
      const float* p = zb + (m * 16 + c15) * DIM + kk * 32 + g * 8;
      a0[m][kk][0] = *(const f32x4*)p;
      a0[m][kk][1] = *(const f32x4*)(p + 4);
    }

  __syncthreads();   // codebook resident (the kernel's only full barrier)

  // ---- chunk-1 A loads: issue now; compiler keeps them early (pack-0 only
  //      waits on a0's vmcnt) and they fly under sweep-0.  NO sched_barrier.
  f32x4 a1[2][2][2];
  #pragma unroll
  for (int m = 0; m < 2; ++m)
    #pragma unroll
    for (int kk = 0; kk < 2; ++kk) {
      const float* p = zb + ((32 + m * 16) + c15) * DIM + kk * 32 + g * 8;
      a1[m][kk][0] = *(const f32x4*)p;
      a1[m][kk][1] = *(const f32x4*)(p + 4);
    }

  const char* bsp = (const char*)B8;
  const int slot = (g ^ (c15 & 3)) << 4;   // lane's swizzled 16B chunk in a 64B row
  const f32x4 cv = {128.0f, 128.0f, 128.0f, 128.0f};   // positivity bias
  const f32x4* cb4 = (const f32x4*)cb;
  f32x4* out4 = (f32x4*)out;

  auto pack8 = [&](const f32x4& v0, const f32x4& v1) -> long long {
    unsigned lo = __builtin_amdgcn_cvt_pk_fp8_f32(v0[0], v0[1], 0, false);
    lo = __builtin_amdgcn_cvt_pk_fp8_f32(v0[2], v0[3], lo, true);
    unsigned hi = __builtin_amdgcn_cvt_pk_fp8_f32(v1[0], v1[1], 0, false);
    hi = __builtin_amdgcn_cvt_pk_fp8_f32(v1[2], v1[3], hi, true);
    return (long long)(((unsigned long long)hi << 32) | (unsigned long long)lo);
  };

  float zsq = 0.0f, lossx = 0.0f;

  // ---- one 32-row chunk: pack A, sweep all 1024 codes, epilogue (gather+write)
  auto chunk = [&](f32x4 (&a)[2][2][2], int poff) {
    long long ah[2][2];
    #pragma unroll
    for (int m = 0; m < 2; ++m)
      #pragma unroll
      for (int kk = 0; kk < 2; ++kk) {
        ah[m][kk] = pack8(a[m][kk][0], a[m][kk][1]);
        #pragma unroll
        for (int j = 0; j < 4; ++j)
          zsq += a[m][kk][0][j] * a[m][kk][0][j]
               + a[m][kk][1][j] * a[m][kk][1][j];
      }

    unsigned best[2][4];
    #pragma unroll
    for (int m = 0; m < 2; ++m)
      #pragma unroll
      for (int r = 0; r < 4; ++r) best[m][r] = 0u;

    auto LDB = [&](int t, llx2& b0, llx2& b1) {
      const int r0 = (t * 32 + c15) * 64;
      b0 = *(const llx2*)(bsp + r0 + slot);           // n=0: kk0 8B | kk1 8B
      b1 = *(const llx2*)(bsp + r0 + 1024 + slot);    // n=1 (+16 codes * 64B)
    };
    auto MM = [&](int t, llx2 b0, llx2 b1) {
      f32x4 acc[2][2];
      __builtin_amdgcn_s_setprio(1);
      #pragma unroll
      for (int n = 0; n < 2; ++n) {
        const llx2 f = n ? b1 : b0;
        #pragma unroll
        for (int m = 0; m < 2; ++m) {
          acc[n][m] = __builtin_amdgcn_mfma_f32_16x16x32_fp8_fp8(
              ah[m][0], f[0], cv, 0, 0, 0);
          acc[n][m] = __builtin_amdgcn_mfma_f32_16x16x32_fp8_fp8(
              ah[m][1], f[1], acc[n][m], 0, 0, 0);
        }
      }
      __builtin_amdgcn_s_setprio(0);
      const unsigned cc0 = 1023u - (unsigned)(t * 32 + c15);
      #pragma unroll
      for (int m = 0; m < 2; ++m)
        #pragma unroll
        for (int r = 0; r < 4; ++r) {
          const unsigned k0 =
              (__builtin_bit_cast(unsigned, acc[0][m][r]) & kmask) | cc0;
          const unsigned k1 =
              (__builtin_bit_cast(unsigned, acc[1][m][r]) & kmask) | (cc0 - 16u);
          const unsigned kp = k0 > k1 ? k0 : k1;             // \  v_max3_u32
          best[m][r] = kp > best[m][r] ? kp : best[m][r];    // /
        }
    };

    llx2 x0, x1, y0, y1;
    LDB(0, x0, x1);
    #pragma unroll 1
    for (int t2 = 0; t2 < 16; ++t2) {
      LDB(t2 * 2 + 1, y0, y1);
      MM(t2 * 2, x0, x1);
      LDB((t2 * 2 + 2) & 31, x0, x1);   // last wraps to 0 (unused)
      MM(t2 * 2 + 1, y0, y1);
    }

    // epilogue: winner resolve, gather cb row -> out (fire-and-forget), loss
    #pragma unroll
    for (int m = 0; m < 2; ++m)
      #pragma unroll
      for (int r = 0; r < 4; ++r) {
        unsigned bk = best[m][r];
        #pragma unroll
        for (int w = 1; w < 16; w <<= 1) {
          const unsigned ob = (unsigned)__shfl_xor((int)bk, w, 64);
          bk = ob > bk ? ob : bk;
        }
        const int row = poff + m * 16 + g * 4 + r;
        const int bi = 1023 - (int)(bk & 1023u);
        out4[(wrow + row) * 16 + c15] = cb4[bi * 16 + c15];
        if (c15 == 0)
          lossx += (128.0f - __builtin_bit_cast(float, bk & kmask)) + eps2[bi];
      }
  };

  chunk(a0, 0);    // chunk-1 loads in flight; chunk-0 writes drain under sweep-1
  chunk(a1, 32);

  // ---- per-block loss partial -> single fire-and-forget float atomicAdd
  float psum = zsq + lossx * (1.0f / 512.0f);
  #pragma unroll
  for (int w = 32; w >= 1; w >>= 1) psum += __shfl_xor(psum, w, 64);
  if (lane == 0) sml[wv] = psum;
  __syncthreads();
  if (tid == 0) {
    const float t = sml[0] + sml[1] + sml[2] + sml[3];
    atomicAdd(out + (size_t)N_TOKENS * DIM,
              t * (1.25f / (float)((size_t)N_TOKENS * DIM)));
  }
}

extern "C" void kernel_launch(void* const* d_in, const int* in_sizes, int n_in,
                              void* d_out, int out_size, void* d_ws, size_t ws_size,
                              hipStream_t stream) {
  const float* z = (const float*)d_in[0];
  const float* cb = (const float*)d_in[1];
  float* out = (float*)d_out;
  char* ws = (char*)d_ws;

  // workspace layout (69632 bytes used)
  unsigned* ch8 = (unsigned*)(ws);               // 64 KB fp8 codebook (permuted)
  float* eps2 = (float*)(ws + 65536);            // 4 KB  ||E'||^2/2048

  (void)hipFuncSetAttribute((const void*)vq_argmin,
                            hipFuncAttributeMaxDynamicSharedMemorySize, DYN_LDS);

  vq_prep8<<<64, 256, 0, stream>>>(cb, ch8, eps2, out + (size_t)N_TOKENS * DIM);
  vq_argmin<<<512, 256, DYN_LDS, stream>>>(z, ch8, eps2, cb, out);
}

// Round 18
// 30.814 us; speedup vs baseline: 1.1592x; 1.1592x over previous
//
#include <hip/hip_runtime.h>

// VectorQuantizer on MI355X (gfx950) — v18 = v12 verbatim (measured best: 30.8us).
// out[0 .. 8388607] = codebook[argmin_k ||z - E_k||^2]   (f32)
// out[8388608]      = 1.25 * mean((z_q - z)^2)           (f32)
//
// Score: maximize  s + ca,  s = fp8(z).fp8(1024 E_k) via mfma_f32_16x16x32_fp8_fp8,
// ca = 128 - ||1024 E_k||^2/2048 (exact f32) as the MFMA C-operand.
// Key = (bits(s+ca) & 0xFFFFFC00) | (1023-col); u32 max = argmax + earliest-col
// tie-break (np.argmin rule).  Loss: ||q-z||^2_row = ||z||^2_f32 + (128 - v*)/512.
//
// Final structure (9 families tested, rounds 1-17): 512 blocks x 512 thr,
// 2 blocks/CU (68 KB LDS), persistent fp8 codebook in LDS staged once via
// global_load_lds (source-XOR-swizzled, dest linear), 32 rows/wave, single
// barrier, ping-pong B+ca registers, key-packed argmax, fused gather+loss.
// Refuted alternatives: bf16 sweeps (v7/v8), barrier-staged rings (v3/v4),
// ACQ_REL finalize (v6/v9), reg-staged prep (v6), 256-thr 2-chunk (v14/v17),
// oversubscription (v15), TLP beyond 2 blocks/CU helps ~0 (v12 vs v10).

typedef __attribute__((ext_vector_type(4))) float f32x4;
typedef __attribute__((ext_vector_type(2))) long long llx2;

#define N_TOKENS 131072
#define DIM 64
#define DYN_LDS 69632   // 64 KB fp8 codebook (permuted) + 4 KB ca

// ---------------- kernel 1: codebook prep (fp8 permuted + ca) -----------------
// Permuted row layout, byte b (0..63): c=b>>4 (16B chunk), kk=(b>>3)&1, j=b&7
// holds fp8(E'[kk*32 + c*8 + j]) -> one 16B chunk = one g-group's (kk0,kk1) pair.
__global__ __launch_bounds__(256) void vq_prep8(
    const float* __restrict__ cb, unsigned* __restrict__ ch8,
    float* __restrict__ ca2) {
  const int t = threadIdx.x;
  const int code = blockIdx.x * 16 + (t >> 4);   // 64 blocks * 16 codes
  const int l = t & 15;                          // dword slot within 64B row
  const int k0 = ((l >> 1) & 1) * 32 + (l >> 2) * 8 + (l & 1) * 4;
  const f32x4 v = *(const f32x4*)(cb + code * DIM + k0);
  const float e0 = v[0] * 1024.0f, e1 = v[1] * 1024.0f;
  const float e2 = v[2] * 1024.0f, e3 = v[3] * 1024.0f;
  unsigned p = __builtin_amdgcn_cvt_pk_fp8_f32(e0, e1, 0, false);
  p = __builtin_amdgcn_cvt_pk_fp8_f32(e2, e3, p, true);
  ch8[code * 16 + l] = p;
  float sq = e0 * e0 + e1 * e1 + e2 * e2 + e3 * e3;
  #pragma unroll
  for (int w = 1; w < 16; w <<= 1) sq += __shfl_xor(sq, w, 64);
  if (l == 0) ca2[code] = 128.0f - sq * (1.0f / 2048.0f);
}

// ---------------- kernel 2: persistent-codebook argmin, 2 blocks/CU -----------
__global__ __attribute__((amdgpu_flat_work_group_size(512, 512),
                          amdgpu_waves_per_eu(4, 4)))
void vq_argmin(
    const float* __restrict__ z, const unsigned* __restrict__ ch8,
    const float* __restrict__ ca2, const float* __restrict__ cb,
    float* __restrict__ out, double* __restrict__ part) {
  extern __shared__ char lds[];
  unsigned* B8 = (unsigned*)lds;                 // 64 KB: [1024 codes][16 dwords]
  float* ca_s = (float*)(lds + 65536);           // 4 KB
  __shared__ float sml[8];

  const int tid = threadIdx.x, lane = tid & 63, wv = tid >> 6;
  const int g = lane >> 4, c15 = lane & 15;
  const size_t wrow = (size_t)blockIdx.x * 256 + (size_t)wv * 32;  // 32 rows/wave
  const unsigned kmask = 0xFFFFFC00u;

  // ---- DMA-stage fp8 codebook (+ca); source XOR-swizzled 16B chunks, dest linear
  #pragma unroll
  for (int q = 0; q < 8; ++q) {
    const int chunk = q * 512 + tid;             // 16B chunk id, 0..4095
    const int code = chunk >> 2, c2 = chunk & 3;
    __builtin_amdgcn_global_load_lds(
        (const __attribute__((address_space(1))) unsigned int*)
            (ch8 + code * 16 + ((c2 ^ (code & 3)) << 2)),
        (__attribute__((address_space(3))) unsigned int*)(B8 + chunk * 4),
        16, 0, 0);
  }
  if (tid < 256)
    __builtin_amdgcn_global_load_lds(
        (const __attribute__((address_space(1))) unsigned int*)(ca2 + tid * 4),
        (__attribute__((address_space(3))) unsigned int*)(ca_s + tid * 4),
        16, 0, 0);

  // ---- A loads (the wave's 32 rows), in flight across the barrier
  f32x4 a[2][2][2];
  const float* zb = z + wrow * DIM;
  #pragma unroll
  for (int m = 0; m < 2; ++m)
    #pragma unroll
    for (int kk = 0; kk < 2; ++kk) {
      const float* p = zb + (m * 16 + c15) * DIM + kk * 32 + g * 8;
      a[m][kk][0] = *(const f32x4*)p;
      a[m][kk][1] = *(const f32x4*)(p + 4);
    }

  __syncthreads();   // codebook + ca resident (the kernel's only full barrier)

  // ---- convert A to fp8 + exact-f32 zsq
  float zsq = 0.0f;
  auto pack8 = [&](const f32x4& v0, const f32x4& v1) -> long long {
    unsigned lo = __builtin_amdgcn_cvt_pk_fp8_f32(v0[0], v0[1], 0, false);
    lo = __builtin_amdgcn_cvt_pk_fp8_f32(v0[2], v0[3], lo, true);
    unsigned hi = __builtin_amdgcn_cvt_pk_fp8_f32(v1[0], v1[1], 0, false);
    hi = __builtin_amdgcn_cvt_pk_fp8_f32(v1[2], v1[3], hi, true);
    return (long long)(((unsigned long long)hi << 32) | (unsigned long long)lo);
  };
  long long ah[2][2];
  #pragma unroll
  for (int m = 0; m < 2; ++m)
    #pragma unroll
    for (int kk = 0; kk < 2; ++kk) {
      ah[m][kk] = pack8(a[m][kk][0], a[m][kk][1]);
      #pragma unroll
      for (int j = 0; j < 4; ++j)
        zsq += a[m][kk][0][j] * a[m][kk][0][j]
             + a[m][kk][1][j] * a[m][kk][1][j];
    }

  // ---- single sweep: 32 rows x all 1024 codes, ping-pong B+ca regs
  unsigned best[2][4];
  #pragma unroll
  for (int m = 0; m < 2; ++m)
    #pragma unroll
    for (int r = 0; r < 4; ++r) best[m][r] = 0u;

  const char* bsp = (const char*)B8;
  const int slot = (g ^ (c15 & 3)) << 4;   // lane's swizzled 16B chunk in a 64B row

  auto LDB = [&](int t, llx2& b0, llx2& b1, float& cA, float& cB) {
    const int r0 = (t * 32 + c15) * 64;
    b0 = *(const llx2*)(bsp + r0 + slot);           // n=0: kk0 8B | kk1 8B
    b1 = *(const llx2*)(bsp + r0 + 1024 + slot);    // n=1 (+16 codes * 64B)
    cA = ca_s[t * 32 + c15];
    cB = ca_s[t * 32 + 16 + c15];
  };
  auto MM = [&](int t, llx2 b0, llx2 b1, float cA, float cB) {
    f32x4 acc[2][2];
    __builtin_amdgcn_s_setprio(1);
    #pragma unroll
    for (int n = 0; n < 2; ++n) {
      const llx2 f = n ? b1 : b0;
      const float can = n ? cB : cA;
      const f32x4 cv = {can, can, can, can};
      #pragma unroll
      for (int m = 0; m < 2; ++m) {
        acc[n][m] = __builtin_amdgcn_mfma_f32_16x16x32_fp8_fp8(
            ah[m][0], f[0], cv, 0, 0, 0);
        acc[n][m] = __builtin_amdgcn_mfma_f32_16x16x32_fp8_fp8(
            ah[m][1], f[1], acc[n][m], 0, 0, 0);
      }
    }
    __builtin_amdgcn_s_setprio(0);
    #pragma unroll
    for (int n = 0; n < 2; ++n) {
      const unsigned cc = 1023u - (unsigned)(t * 32 + n * 16 + c15);
      #pragma unroll
      for (int m = 0; m < 2; ++m)
        #pragma unroll
        for (int r = 0; r < 4; ++r) {
          const unsigned key =
              (__builtin_bit_cast(unsigned, acc[n][m][r]) & kmask) | cc;
          best[m][r] = key > best[m][r] ? key : best[m][r];   // v_max_u32
        }
    }
  };

  llx2 x0, x1, y0, y1;
  float cx0, cx1, cy0, cy1;
  LDB(0, x0, x1, cx0, cx1);
  #pragma unroll 1
  for (int t2 = 0; t2 < 16; ++t2) {
    LDB(t2 * 2 + 1, y0, y1, cy0, cy1);
    MM(t2 * 2, x0, x1, cx0, cx1);
    LDB((t2 * 2 + 2) & 31, x0, x1, cx0, cx1);   // last wraps to 0 (unused)
    MM(t2 * 2 + 1, y0, y1, cy0, cy1);
  }

  // ---- epilogue: in-wave winner resolve, gather cb row -> out, loss partial
  float lossx = 0.0f;
  const f32x4* cb4 = (const f32x4*)cb;
  f32x4* out4 = (f32x4*)out;
  #pragma unroll
  for (int m = 0; m < 2; ++m)
    #pragma unroll
    for (int r = 0; r < 4; ++r) {
      unsigned bk = best[m][r];
      #pragma unroll
      for (int w = 1; w < 16; w <<= 1) {
        const unsigned ob = (unsigned)__shfl_xor((int)bk, w, 64);
        bk = ob > bk ? ob : bk;
      }
      const int row = m * 16 + g * 4 + r;          // within wave's 32
      const int bi = 1023 - (int)(bk & 1023u);
      out4[(wrow + row) * 16 + c15] = cb4[bi * 16 + c15];
      if (c15 == 0) lossx += 128.0f - __builtin_bit_cast(float, bk & kmask);
    }

  // ---- per-block loss partial (deterministic; plain store, NO atomics)
  float psum = zsq + lossx * (1.0f / 512.0f);
  #pragma unroll
  for (int w = 32; w >= 1; w >>= 1) psum += __shfl_xor(psum, w, 64);
  if (lane == 0) sml[wv] = psum;
  __syncthreads();
  if (tid == 0) {
    double t = 0.0;
    #pragma unroll
    for (int i = 0; i < 8; ++i) t += (double)sml[i];
    part[blockIdx.x] = t;
  }
}

// ---------------- kernel 3: finalize loss (deterministic tree) ----------------
__global__ __launch_bounds__(256) void vq_finalize(
    const double* __restrict__ part, float* __restrict__ out_loss) {
  __shared__ double s[4];
  const int tid = threadIdx.x, lane = tid & 63, wv = tid >> 6;
  double v = part[tid] + part[tid + 256];
  #pragma unroll
  for (int w = 32; w >= 1; w >>= 1) v += __shfl_xor(v, w, 64);
  if (lane == 0) s[wv] = v;
  __syncthreads();
  if (tid == 0)
    out_loss[0] = (float)(1.25 * (s[0] + s[1] + s[2] + s[3]) /
                          ((double)N_TOKENS * (double)DIM));
}

extern "C" void kernel_launch(void* const* d_in, const int* in_sizes, int n_in,
                              void* d_out, int out_size, void* d_ws, size_t ws_size,
                              hipStream_t stream) {
  const float* z = (const float*)d_in[0];
  const float* cb = (const float*)d_in[1];
  float* out = (float*)d_out;
  char* ws = (char*)d_ws;

  // workspace layout (73728 bytes used)
  unsigned* ch8 = (unsigned*)(ws);               // 64 KB fp8 codebook (permuted)
  float* ca2 = (float*)(ws + 65536);             // 4 KB  128 - ||E'||^2/2048
  double* part = (double*)(ws + 69632);          // 4 KB  per-block loss partials (512)

  (void)hipFuncSetAttribute((const void*)vq_argmin,
                            hipFuncAttributeMaxDynamicSharedMemorySize, DYN_LDS);

  vq_prep8<<<64, 256, 0, stream>>>(cb, ch8, ca2);
  vq_argmin<<<512, 512, DYN_LDS, stream>>>(z, ch8, ca2, cb, out, part);
  vq_finalize<<<1, 256, 0, stream>>>(part, out + (size_t)N_TOKENS * DIM);
}